// Round 1
// 998.296 us; speedup vs baseline: 1.0710x; 1.0710x over previous
//
#include <hip/hip_runtime.h>

typedef __bf16 bf16_t;
typedef __attribute__((ext_vector_type(8))) __bf16 bf16x8;
typedef __attribute__((ext_vector_type(4))) __bf16 bf16x4;
typedef __attribute__((ext_vector_type(4))) float f32x4;

// ---------------------------------------------------------------- helpers
__device__ __forceinline__ void async_copy16(const bf16_t* g, bf16_t* l) {
    __builtin_amdgcn_global_load_lds(
        (const __attribute__((address_space(1))) void*)g,
        (__attribute__((address_space(3))) void*)l, 16, 0, 0);
}

// ---------------------------------------------------------------- f32 -> bf16 elementwise (4 elems/thread)
__global__ __launch_bounds__(256) void cvt_bf16(const float* __restrict__ in,
                                                bf16_t* __restrict__ out) {
    int i = (blockIdx.x * 256 + threadIdx.x) * 4;
    float4 v = *(const float4*)(in + i);
    bf16x4 o;
    o[0] = (__bf16)v.x; o[1] = (__bf16)v.y; o[2] = (__bf16)v.z; o[3] = (__bf16)v.w;
    *(bf16x4*)(out + i) = o;
}

// ---------------------------------------------------------------- grouped W [K,1024] f32 -> Wt [parts*1024, K] bf16
__global__ __launch_bounds__(256) void transpose_group(const float* __restrict__ s0,
                                                       const float* __restrict__ s1,
                                                       const float* __restrict__ s2,
                                                       bf16_t* __restrict__ dst, int K) {
    const float* in;
    if (blockIdx.z == 0) in = s0;
    else if (blockIdx.z == 1) in = s1;
    else in = s2;
    bf16_t* out = dst + (size_t)blockIdx.z * 1024 * K;
    __shared__ float tile[32][33];
    int t = threadIdx.x;
    int tx = t & 31, ty = t >> 5;              // 32 x 8
    int n0 = blockIdx.x * 32, k0 = blockIdx.y * 32;
#pragma unroll
    for (int i = 0; i < 4; i++) {
        int k = k0 + ty + i * 8;
        tile[ty + i * 8][tx] = in[(size_t)k * 1024 + n0 + tx];
    }
    __syncthreads();
#pragma unroll
    for (int i = 0; i < 4; i++) {
        int n = n0 + ty + i * 8;
        out[(size_t)n * K + k0 + tx] = (bf16_t)tile[tx][ty + i * 8];
    }
}

// fused bias: out[0..1023] = src, out[1024..2047] = 0
__global__ __launch_bounds__(256) void fuse_bias(const float* __restrict__ src,
                                                 float* __restrict__ out) {
    int i = blockIdx.x * 256 + threadIdx.x;
    out[i] = (i < 1024) ? src[i] : 0.f;
}

// ---------------------------------------------------------------- GEMM 256x256 tile, 8 waves, BK=32,
// 4-deep rotating LDS buffers with counted vmcnt (never 0 in main loop), pair-row XOR swizzle
// (conflict-free ds_read_b128), setprio around MFMA clusters, XCD-aware block swizzle.
// [M,N] = A[M,K](bf16) @ Bt[N,K]^T (+bias). Column segment c/1024 -> o{0,1,2}, row stride 1024.
__global__ __launch_bounds__(512, 2) void gemm256(const bf16_t* __restrict__ A,
                                                  const bf16_t* __restrict__ Bt,
                                                  const float* __restrict__ bias,
                                                  bf16_t* __restrict__ o0,
                                                  bf16_t* __restrict__ o1,
                                                  bf16_t* __restrict__ o2,
                                                  int M, int N, int K) {
    (void)M; (void)N;
    // 4 buffers x (A 256x32 + B 256x32) bf16 = 4 x 16384 elems = 128 KiB
    __shared__ bf16_t Ls[65536];
    const int t = threadIdx.x;
    const int w = t >> 6, lane = t & 63;
    const int l16 = lane & 15, quad = lane >> 4;
    const int wm2 = w >> 2, wn4 = w & 3;       // 2x4 wave grid; wave tile 128x64

    // XCD-aware swizzle (every grid here is a multiple of 8 workgroups -> bijective)
    const int nx = gridDim.x;                  // M/256
    const int nwg = nx * gridDim.y;
    const int flat = blockIdx.y * nx + blockIdx.x;
    const int chunk = nwg >> 3;
    const int swz = (flat & 7) * chunk + (flat >> 3);
    const int bm = (swz % nx) * 256;
    const int bn = (swz / nx) * 256;

    const int NT = K >> 5;                     // K-tiles of 32

    // ---- staging constants (pair-row swizzle: 16B slot s ^= (pair_row & 7)) ----
    const int sl = t & 7;                      // linear 16B slot within 128B pair-row
    const int pl = (t >> 3) & 63;              // pair-row within 8KB round
    const int ss = sl ^ (pl & 7);              // unswizzled slot -> global chunk
    const int srow = (pl << 1) | (ss >> 2);    // global row 0..127 within round 0
    const int scol = (ss & 3) << 3;            // element col within BK=32
    const bf16_t* gA = A + (size_t)(bm + srow) * K + scol;
    const bf16_t* gB = Bt + (size_t)(bn + srow) * K + scol;
    const size_t rstep = (size_t)128 * K;      // +128 rows for round 1
    const int ldW = w * 512;                   // wave-uniform LDS stage base (elems)

    // ---- swizzled read offsets (element units), constant across K-loop ----
    int offA[8], offB[4];
#pragma unroll
    for (int mf = 0; mf < 8; mf++) {
        int row = wm2 * 128 + mf * 16 + l16;
        int p = row >> 1;
        int s2 = (((row & 1) << 2) | quad) ^ (p & 7);
        offA[mf] = p * 64 + s2 * 8;
    }
#pragma unroll
    for (int nf = 0; nf < 4; nf++) {
        int row = wn4 * 64 + nf * 16 + l16;
        int p = row >> 1;
        int s2 = (((row & 1) << 2) | quad) ^ (p & 7);
        offB[nf] = 8192 + p * 64 + s2 * 8;
    }

    const f32x4 zero = {0.f, 0.f, 0.f, 0.f};
    f32x4 acc[8][4];
#pragma unroll
    for (int i = 0; i < 8; i++)
#pragma unroll
        for (int j = 0; j < 4; j++) acc[i][j] = zero;

    // ---- prologue: stage K-tiles 0..2 (NT >= 32 always) ----
#pragma unroll
    for (int pt = 0; pt < 3; pt++) {
        bf16_t* lb = Ls + pt * 16384 + ldW;
        const bf16_t* a0 = gA + pt * 32;
        const bf16_t* b0 = gB + pt * 32;
        async_copy16(a0, lb);                  // A rows   0..127
        async_copy16(a0 + rstep, lb + 4096);   // A rows 128..255
        async_copy16(b0, lb + 8192);           // B rows   0..127
        async_copy16(b0 + rstep, lb + 12288);  // B rows 128..255
    }
    asm volatile("s_waitcnt vmcnt(8)" ::: "memory");  // tile 0 landed; 1,2 in flight
    __builtin_amdgcn_s_barrier();
    __builtin_amdgcn_sched_barrier(0);

    for (int t0 = 0; t0 < NT; t0++) {
        const bf16_t* cb = Ls + (t0 & 3) * 16384;           // compute buffer
        bf16_t* sb = Ls + ((t0 + 3) & 3) * 16384 + ldW;     // stage buffer (free since t0-1)
        const bf16_t* ga = gA + (size_t)(t0 + 3) * 32;
        const bf16_t* gb = gB + (size_t)(t0 + 3) * 32;
        const bool st = (t0 + 3 < NT);
        bf16x8 bq[4], aq[4], ar[4];

        // ---------------- phase A: B frags + A frags 0..3, stage A of tile t0+3
#pragma unroll
        for (int nf = 0; nf < 4; nf++) bq[nf] = *(const bf16x8*)(cb + offB[nf]);
#pragma unroll
        for (int mf = 0; mf < 4; mf++) aq[mf] = *(const bf16x8*)(cb + offA[mf]);
        if (st) {
            async_copy16(ga, sb);
            async_copy16(ga + rstep, sb + 4096);
        }
        __builtin_amdgcn_s_barrier();
        __builtin_amdgcn_s_setprio(1);
#pragma unroll
        for (int mf = 0; mf < 4; mf++)
#pragma unroll
            for (int nf = 0; nf < 4; nf++)
                acc[mf][nf] = __builtin_amdgcn_mfma_f32_16x16x32_bf16(aq[mf], bq[nf], acc[mf][nf], 0, 0, 0);
        __builtin_amdgcn_s_setprio(0);
        __builtin_amdgcn_s_barrier();

        // ---------------- phase B: A frags 4..7, stage B of tile t0+3
#pragma unroll
        for (int mf = 0; mf < 4; mf++) ar[mf] = *(const bf16x8*)(cb + offA[4 + mf]);
        if (st) {
            async_copy16(gb, sb + 8192);
            async_copy16(gb + rstep, sb + 12288);
        }
        __builtin_amdgcn_s_barrier();
        __builtin_amdgcn_s_setprio(1);
#pragma unroll
        for (int mf = 0; mf < 4; mf++)
#pragma unroll
            for (int nf = 0; nf < 4; nf++)
                acc[4 + mf][nf] = __builtin_amdgcn_mfma_f32_16x16x32_bf16(ar[mf], bq[nf], acc[4 + mf][nf], 0, 0, 0);
        __builtin_amdgcn_s_setprio(0);

        // ---------------- gate into tile t0+1: counted vmcnt (4 loads per staged tile)
        if (t0 + 1 < NT) {
            if (t0 + 3 < NT)      asm volatile("s_waitcnt vmcnt(8)" ::: "memory"); // t0+2,t0+3 in flight
            else if (t0 + 2 < NT) asm volatile("s_waitcnt vmcnt(4)" ::: "memory"); // t0+2 in flight
            else                  asm volatile("s_waitcnt vmcnt(0)" ::: "memory");
            __builtin_amdgcn_s_barrier();
            __builtin_amdgcn_sched_barrier(0);
        }
    }

    // ---------------- epilogue: +bias, bf16 store, 3-way column-segment split
    bf16_t* outp;
    if (bn < 1024) outp = o0;
    else if (bn < 2048) outp = o1;
    else outp = o2;
    const int cseg = bn & 1023;
    float bsv[4];
#pragma unroll
    for (int nf = 0; nf < 4; nf++)
        bsv[nf] = bias ? bias[bn + wn4 * 64 + nf * 16 + l16] : 0.f;
#pragma unroll
    for (int mf = 0; mf < 8; mf++) {
        int r0 = bm + wm2 * 128 + mf * 16 + quad * 4;
#pragma unroll
        for (int nf = 0; nf < 4; nf++) {
            int c = cseg + wn4 * 64 + nf * 16 + l16;
#pragma unroll
            for (int r = 0; r < 4; r++)
                outp[(size_t)(r0 + r) * 1024 + c] = (bf16_t)(acc[mf][nf][r] + bsv[nf]);
        }
    }
}

// ---------------------------------------------------------------- fused attention per (b, head) — unchanged (verified R2/R5)
template <int LQ, int LK>
__global__ __launch_bounds__(256) void attn_kernel(const bf16_t* __restrict__ Q,
                                                   const bf16_t* __restrict__ Kb,
                                                   const bf16_t* __restrict__ V,
                                                   const int* __restrict__ qmask,
                                                   const int* __restrict__ kmask,
                                                   bf16_t* __restrict__ O) {
    constexpr int VSTR = LK + 8;
    constexpr int NQT = LQ / 16, NKT = LK / 16, NKB = LK / 32;
    __shared__ bf16_t Vt[256 * VSTR];
    __shared__ bf16_t Pb[4 * 16 * LK];

    const int t = threadIdx.x;
    const int w = t >> 6, lane = t & 63;
    const int quad = lane >> 4, l16 = lane & 15;
    const int b = blockIdx.x >> 2;
    const int h = blockIdx.x & 3;
    const int hoff = h * 256;

    for (int idx = t; idx < LK * 32; idx += 256) {
        int k = idx % LK;
        int e0 = (idx / LK) * 8;
        bf16x8 v = *(const bf16x8*)(V + (size_t)(b * LK + k) * 1024 + hoff + e0);
#pragma unroll
        for (int j = 0; j < 8; j++) Vt[(e0 + j) * VSTR + k] = v[j];
    }
    __syncthreads();

    bf16_t* P = Pb + w * (16 * LK);

    for (int qt = w; qt < NQT; qt += 4) {
        const int qrow = b * LQ + qt * 16;
        bf16x8 qf[8];
#pragma unroll
        for (int kb = 0; kb < 8; kb++)
            qf[kb] = *(const bf16x8*)(Q + (size_t)(qrow + l16) * 1024 + hoff + kb * 32 + quad * 8);

        f32x4 s[NKT];
        const f32x4 zero = {0.f, 0.f, 0.f, 0.f};
#pragma unroll
        for (int nt = 0; nt < NKT; nt++) {
            f32x4 a = zero;
#pragma unroll
            for (int kb = 0; kb < 8; kb++) {
                bf16x8 kf = *(const bf16x8*)(Kb + (size_t)(b * LK + nt * 16 + l16) * 1024 + hoff + kb * 32 + quad * 8);
                a = __builtin_amdgcn_mfma_f32_16x16x32_bf16(qf[kb], kf, a, 0, 0, 0);
            }
            s[nt] = a;
        }

        int km[NKT];
#pragma unroll
        for (int nt = 0; nt < NKT; nt++) km[nt] = kmask[b * LK + nt * 16 + l16];
        int qmv[4];
#pragma unroll
        for (int r = 0; r < 4; r++) qmv[r] = qmask[b * LQ + qt * 16 + quad * 4 + r];

        float rmax[4], rsum[4];
#pragma unroll
        for (int r = 0; r < 4; r++) rmax[r] = -3.0e38f;
#pragma unroll
        for (int nt = 0; nt < NKT; nt++)
#pragma unroll
            for (int r = 0; r < 4; r++) {
                float v = s[nt][r] * 0.0625f;
                bool ok = (qmv[r] != 0) && (km[nt] != 0);
                s[nt][r] = ok ? v : -3.0e38f;
                rmax[r] = fmaxf(rmax[r], s[nt][r]);
            }
#pragma unroll
        for (int r = 0; r < 4; r++)
            for (int off = 1; off < 16; off <<= 1)
                rmax[r] = fmaxf(rmax[r], __shfl_xor(rmax[r], off, 16));
#pragma unroll
        for (int r = 0; r < 4; r++) rsum[r] = 0.f;
#pragma unroll
        for (int nt = 0; nt < NKT; nt++)
#pragma unroll
            for (int r = 0; r < 4; r++) {
                float p = (s[nt][r] > -1.0e38f) ? __expf(s[nt][r] - rmax[r]) : 0.f;
                s[nt][r] = p;
                rsum[r] += p;
            }
#pragma unroll
        for (int r = 0; r < 4; r++)
            for (int off = 1; off < 16; off <<= 1)
                rsum[r] += __shfl_xor(rsum[r], off, 16);
#pragma unroll
        for (int r = 0; r < 4; r++) rsum[r] = (rsum[r] > 0.f) ? 1.f / rsum[r] : 0.f;

#pragma unroll
        for (int nt = 0; nt < NKT; nt++)
#pragma unroll
            for (int r = 0; r < 4; r++)
                P[(quad * 4 + r) * LK + nt * 16 + l16] = (bf16_t)(s[nt][r] * rsum[r]);
        asm volatile("s_waitcnt lgkmcnt(0)" ::: "memory");

        bf16x8 pf[NKB];
#pragma unroll
        for (int kb = 0; kb < NKB; kb++)
            pf[kb] = *(const bf16x8*)(P + l16 * LK + kb * 32 + quad * 8);

#pragma unroll
        for (int et = 0; et < 16; et++) {
            f32x4 o = zero;
#pragma unroll
            for (int kb = 0; kb < NKB; kb++) {
                bf16x8 vf = *(const bf16x8*)(Vt + (et * 16 + l16) * VSTR + kb * 32 + quad * 8);
                o = __builtin_amdgcn_mfma_f32_16x16x32_bf16(pf[kb], vf, o, 0, 0, 0);
            }
#pragma unroll
            for (int r = 0; r < 4; r++)
                O[(size_t)(qrow + quad * 4 + r) * 1024 + hoff + et * 16 + l16] = (bf16_t)o[r];
        }
    }
}

// ---------------------------------------------------------------- LayerNorm over D=1024, eps=1e-3 (bf16 input)
__global__ __launch_bounds__(256) void ln_kernel(const bf16_t* __restrict__ in,
                                                 const float* __restrict__ g,
                                                 const float* __restrict__ be,
                                                 float* __restrict__ outF,
                                                 bf16_t* __restrict__ outB) {
    __shared__ float red[8];
    const int row = blockIdx.x, t = threadIdx.x;
    bf16x4 xb = *(const bf16x4*)(in + (size_t)row * 1024 + t * 4);
    float x0 = (float)xb[0], x1 = (float)xb[1], x2 = (float)xb[2], x3 = (float)xb[3];
    float s = x0 + x1 + x2 + x3;
    float ss = x0 * x0 + x1 * x1 + x2 * x2 + x3 * x3;
    for (int off = 1; off < 64; off <<= 1) {
        s += __shfl_xor(s, off);
        ss += __shfl_xor(ss, off);
    }
    int w = t >> 6, lane = t & 63;
    if (lane == 0) { red[w * 2] = s; red[w * 2 + 1] = ss; }
    __syncthreads();
    if (t == 0) {
        float a = 0.f, b2 = 0.f;
        for (int i = 0; i < 4; i++) { a += red[i * 2]; b2 += red[i * 2 + 1]; }
        red[0] = a; red[1] = b2;
    }
    __syncthreads();
    float mean = red[0] * (1.f / 1024.f);
    float var = red[1] * (1.f / 1024.f) - mean * mean;
    float rstd = rsqrtf(var + 1e-3f);
    float4 gv = *(const float4*)(g + t * 4);
    float4 bv = *(const float4*)(be + t * 4);
    float y0 = (x0 - mean) * rstd * gv.x + bv.x;
    float y1 = (x1 - mean) * rstd * gv.y + bv.y;
    float y2 = (x2 - mean) * rstd * gv.z + bv.z;
    float y3 = (x3 - mean) * rstd * gv.w + bv.w;
    if (outF) {
        float4 o = {y0, y1, y2, y3};
        *(float4*)(outF + (size_t)row * 1024 + t * 4) = o;
    }
    if (outB) {
        bf16x4 o;
        o[0] = (__bf16)y0; o[1] = (__bf16)y1; o[2] = (__bf16)y2; o[3] = (__bf16)y3;
        *(bf16x4*)(outB + (size_t)row * 1024 + t * 4) = o;
    }
}

// ---------------------------------------------------------------- host orchestration
// Workspace plan — total 145 MB (unchanged from R5, proven safe):
//   WB   [0,8MB)      : one rotating transposed-weight buffer (max fused group 8 MB)
//   bias [8MB,9MB)    : two fused 2048-f32 bias vectors
//   arena [9MB,145MB) : MB offsets below, liveness audited per step in comments
extern "C" void kernel_launch(void* const* d_in, const int* in_sizes, int n_in,
                              void* d_out, int out_size, void* d_ws, size_t ws_size,
                              hipStream_t stream) {
    (void)in_sizes; (void)n_in; (void)out_size; (void)ws_size;
    const float* tE = (const float*)d_in[0];   // [128*96,1024]
    const float* iE = (const float*)d_in[1];   // [128*64,2048]
    const int* tMask = (const int*)d_in[2];
    const int* iMask = (const int*)d_in[3];

    const size_t MB = 1048576;
    char* ws = (char*)d_ws;
    bf16_t* WB = (bf16_t*)ws;
    float* biasT = (float*)(ws + 8 * MB);
    float* biasI = biasT + 2048;
    char* AB = ws + 9 * MB;
    auto buf = [&](int mb) { return (bf16_t*)(AB + (size_t)mb * MB); };

    auto TG = [&](int i0, int i1, int i2, int parts, int K) {
        transpose_group<<<dim3(32, K / 32, parts), 256, 0, stream>>>(
            (const float*)d_in[i0], i1 >= 0 ? (const float*)d_in[i1] : (const float*)d_in[i0],
            i2 >= 0 ? (const float*)d_in[i2] : (const float*)d_in[i0], WB, K);
    };
    auto gemm = [&](const bf16_t* A, const float* bias, bf16_t* out0, bf16_t* out1,
                    bf16_t* out2, int M, int N, int K) {
        gemm256<<<dim3(M / 256, N / 256), 512, 0, stream>>>(A, WB, bias, out0, out1, out2, M, N, K);
    };

    fuse_bias<<<8, 256, 0, stream>>>((const float*)d_in[5], biasT);
    fuse_bias<<<8, 256, 0, stream>>>((const float*)d_in[7], biasI);

    // 1. TB = bf16(tE) @ buf(88) [88,112); [W_tp|ta_Wv]: tP -> 32, taV -> 64. TB dead after.
    cvt_bf16<<<12288, 256, 0, stream>>>(tE, buf(88));
    TG(4, 10, -1, 2, 1024);
    gemm(buf(88), biasT, buf(32), buf(64), nullptr, 12288, 2048, 1024);
    // 2. IB = bf16(iE) @ buf(88) [88,120); [W_ip|ia_Wv]: iP -> 0, iaV -> 16. IB dead after.
    cvt_bf16<<<16384, 256, 0, stream>>>(iE, buf(88));
    TG(6, 14, -1, 2, 2048);
    gemm(buf(88), biasI, buf(0), buf(16), nullptr, 8192, 2048, 2048);
    // 3. [ta_Wk|ia_Wq] <- tP(32):  taK -> 88, iaQ -> 112   (tP dead after)
    TG(9, 12, -1, 2, 1024);
    gemm(buf(32), nullptr, buf(88), buf(112), nullptr, 12288, 2048, 1024);
    // 4. [ta_Wq|ia_Wk] <- iP(0):   taQ -> 32, iaK -> 48    (iP dead after)
    TG(8, 13, -1, 2, 1024);
    gemm(buf(0), nullptr, buf(32), buf(48), nullptr, 8192, 2048, 1024);
    // 5. attn ta: Q=taQ(32) K=taK(88) V=taV(64) -> taO 0   (taQ,taK,taV dead after)
    attn_kernel<64, 96><<<512, 256, 0, stream>>>(buf(32), buf(88), buf(64), iMask, tMask, buf(0));
    // 6. attn ia: Q=iaQ(112) K=iaK(48) V=iaV(16) -> iaO 64
    attn_kernel<96, 64><<<512, 256, 0, stream>>>(buf(112), buf(48), buf(16), tMask, iMask, buf(64));
    // 7. ta_Wo <- taO(0) -> lnin 32; LN -> tLN 88
    TG(11, -1, -1, 1, 1024);
    gemm(buf(0), nullptr, buf(32), nullptr, nullptr, 8192, 1024, 1024);
    ln_kernel<<<8192, 256, 0, stream>>>(buf(32), (const float*)d_in[24], (const float*)d_in[25], nullptr, buf(88));
    // 8. ia_Wo <- iaO(64) -> lnin 0; LN -> iLN 104
    TG(15, -1, -1, 1, 1024);
    gemm(buf(64), nullptr, buf(0), nullptr, nullptr, 12288, 1024, 1024);
    ln_kernel<<<12288, 256, 0, stream>>>(buf(0), (const float*)d_in[26], (const float*)d_in[27], nullptr, buf(104));
    // 9. [ts_Wq|ts_Wk|ts_Wv] <- tLN(88): tsQ 0, tsK 16, tsV 32
    TG(16, 17, 18, 3, 1024);
    gemm(buf(88), nullptr, buf(0), buf(16), buf(32), 8192, 3072, 1024);
    // 10. attn ts -> tsO 48
    attn_kernel<64, 64><<<512, 256, 0, stream>>>(buf(0), buf(16), buf(32), iMask, iMask, buf(48));
    // 11. ts_Wo <- tsO(48) -> lnin 64; LN -> d_out (text, f32)
    TG(19, -1, -1, 1, 1024);
    gemm(buf(48), nullptr, buf(64), nullptr, nullptr, 8192, 1024, 1024);
    ln_kernel<<<8192, 256, 0, stream>>>(buf(64), (const float*)d_in[28], (const float*)d_in[29], (float*)d_out, nullptr);
    // 12. [is_Wq|is_Wk|is_Wv] <- iLN(104): isQ 0, isK 24, isV 48
    TG(20, 21, 22, 3, 1024);
    gemm(buf(104), nullptr, buf(0), buf(24), buf(48), 12288, 3072, 1024);
    // 13. attn is -> isO 72
    attn_kernel<96, 96><<<512, 256, 0, stream>>>(buf(0), buf(24), buf(48), tMask, tMask, buf(72));
    // 14. is_Wo <- isO(72) -> lnin 96; LN -> d_out+8M (image, f32)
    TG(23, -1, -1, 1, 1024);
    gemm(buf(72), nullptr, buf(96), nullptr, nullptr, 12288, 1024, 1024);
    ln_kernel<<<12288, 256, 0, stream>>>(buf(96), (const float*)d_in[30], (const float*)d_in[31],
                                         (float*)d_out + 8388608, nullptr);
}